// Round 15
// baseline (294.343 us; speedup 1.0000x reference)
//
#include <hip/hip_runtime.h>
#include <hip/hip_bf16.h>
#include <type_traits>

// Problem constants
constexpr int SEQ = 4096;
constexpr int DMODEL = 1024;
constexpr int NH = 16;
constexpr int DKH = 64;          // head dim
constexpr float SCALE = 0.125f;  // 1/sqrt(64)

typedef __bf16 bf16x8 __attribute__((ext_vector_type(8)));
typedef __bf16 bf16x4 __attribute__((ext_vector_type(4)));
typedef float f32x4 __attribute__((ext_vector_type(4)));

__device__ inline void store_c(__hip_bfloat16* p, float v) { *p = __float2bfloat16(v); }
__device__ inline void store_c(float* p, float v) { *p = v; }

typedef const void __attribute__((address_space(1)))* gas_ptr;
typedef void __attribute__((address_space(3)))* las_ptr;
__device__ inline void load_lds_16B(const void* g, void* l) {
  __builtin_amdgcn_global_load_lds((gas_ptr)g, (las_ptr)l, 16, 0, 0);
}

// ---------------------------------------------------------------------------
// Fused fp32 -> bf16 conversion for all 7 tensors — identical to R14.
// ---------------------------------------------------------------------------
__global__ __launch_bounds__(256)
void cvt_all(const float* __restrict__ q, const float* __restrict__ k,
             const float* __restrict__ v, const float* __restrict__ wq,
             const float* __restrict__ wk, const float* __restrict__ wv,
             const float* __restrict__ wo,
             __bf16* __restrict__ Xq, __bf16* __restrict__ Xk,
             __bf16* __restrict__ Xv, __bf16* __restrict__ Wqb,
             __bf16* __restrict__ Wkb, __bf16* __restrict__ Wvb,
             __bf16* __restrict__ Wob) {
  const int b = blockIdx.x;
  const float* src; __bf16* dst; size_t base;
  if      (b < 2048) { src = q;  dst = Xq;  base = b; }
  else if (b < 4096) { src = k;  dst = Xk;  base = b - 2048; }
  else if (b < 6144) { src = v;  dst = Xv;  base = b - 4096; }
  else if (b < 6656) { src = wq; dst = Wqb; base = b - 6144; }
  else if (b < 7168) { src = wk; dst = Wkb; base = b - 6656; }
  else if (b < 7680) { src = wv; dst = Wvb; base = b - 7168; }
  else               { src = wo; dst = Wob; base = b - 7680; }
  const size_t i = (base * 256 + threadIdx.x) * 8;
  const float4 a = *(const float4*)(src + i);
  const float4 c = *(const float4*)(src + i + 4);
  bf16x8 r = {(__bf16)a.x, (__bf16)a.y, (__bf16)a.z, (__bf16)a.w,
              (__bf16)c.x, (__bf16)c.y, (__bf16)c.z, (__bf16)c.w};
  *(bf16x8*)(dst + i) = r;
}

// ---------------------------------------------------------------------------
// R15: FUSED 3-projection GEMM. gridDim.z selects {Q,K,V}; 3072 blocks =
// 12 blocks/CU requested (LDS 16 KB caps ~10) vs 4 when launched separately —
// DMA/barrier stalls of one block overlap MFMA of another (m114 lesson).
// Body identical to R14 gemm_bf16_lds (m97 staging, 64x64xBK64).
// z=2 (V) stores transposed (Vt). Q pre-scaled by 1/sqrt(d_k).
// ---------------------------------------------------------------------------
constexpr int BK = 64;

__global__ __launch_bounds__(256)
void gemm3_proj(const __bf16* __restrict__ Xq, const __bf16* __restrict__ Xk,
                const __bf16* __restrict__ Xv,
                const __bf16* __restrict__ Wqb, const __bf16* __restrict__ Wkb,
                const __bf16* __restrict__ Wvb,
                const float* __restrict__ bq, const float* __restrict__ bk,
                const float* __restrict__ bv,
                __hip_bfloat16* __restrict__ Qp, __hip_bfloat16* __restrict__ Kp,
                __hip_bfloat16* __restrict__ Vt) {
  __shared__ alignas(16) __bf16 As[64][64];  // 8 KB
  __shared__ alignas(16) __bf16 Ws[64][64];  // 8 KB

  const int z = blockIdx.z;
  const __bf16* A = (z == 0) ? Xq : (z == 1) ? Xk : Xv;
  const __bf16* W = (z == 0) ? Wqb : (z == 1) ? Wkb : Wvb;
  const float* bias = (z == 0) ? bq : (z == 1) ? bk : bv;
  const float out_scale = (z == 0) ? SCALE : 1.0f;

  const int t = threadIdx.x;
  const int lane = t & 63;
  const int w = t >> 6;
  const int wr = w >> 1;
  const int wc = w & 1;
  const int col = lane & 15;
  const int quad = lane >> 4;
  const int m_blk = blockIdx.y * 64;
  const int n_blk = blockIdx.x * 64;

  const int srow = t >> 3;
  const int scol = (t & 7) * 8;

  f32x4 acc[2][2] = {};

  for (int k0 = 0; k0 < DMODEL; k0 += BK) {
    __syncthreads();
    #pragma unroll
    for (int p = 0; p < 2; ++p)
      load_lds_16B(A + (size_t)(m_blk + p * 32 + srow) * DMODEL + k0 + scol,
                   &As[p * 32 + srow][scol]);
    #pragma unroll
    for (int p = 0; p < 2; ++p)
      load_lds_16B(W + (size_t)(n_blk + p * 32 + srow) * DMODEL + k0 + scol,
                   &Ws[p * 32 + srow][scol]);
    __syncthreads();

    #pragma unroll
    for (int kh = 0; kh < BK; kh += 32) {
      bf16x8 af[2], bfr[2];
      #pragma unroll
      for (int at = 0; at < 2; ++at)
        af[at] = *(const bf16x8*)&As[wr * 32 + at * 16 + col][kh + quad * 8];
      #pragma unroll
      for (int bt = 0; bt < 2; ++bt)
        bfr[bt] = *(const bf16x8*)&Ws[wc * 32 + bt * 16 + col][kh + quad * 8];
      #pragma unroll
      for (int at = 0; at < 2; ++at)
        #pragma unroll
        for (int bt = 0; bt < 2; ++bt)
          acc[at][bt] = __builtin_amdgcn_mfma_f32_16x16x32_bf16(
              af[at], bfr[bt], acc[at][bt], 0, 0, 0);
    }
  }

  #pragma unroll
  for (int at = 0; at < 2; ++at) {
    #pragma unroll
    for (int bt = 0; bt < 2; ++bt) {
      const int n = n_blk + wc * 32 + bt * 16 + col;
      const float b = bias[n];
      #pragma unroll
      for (int i = 0; i < 4; ++i) {
        const int m = m_blk + wr * 32 + at * 16 + quad * 4 + i;
        const float v = (acc[at][bt][i] + b) * out_scale;
        if (z == 2)      Vt[(size_t)n * SEQ + m] = __float2bfloat16(v);
        else if (z == 1) Kp[(size_t)m * DMODEL + n] = __float2bfloat16(v);
        else             Qp[(size_t)m * DMODEL + n] = __float2bfloat16(v);
      }
    }
  }
}

// ---------------------------------------------------------------------------
// Single GEMM (final projection) — identical to R14 gemm_bf16_lds.
// ---------------------------------------------------------------------------
template <typename TC, bool TRANS_C>
__global__ __launch_bounds__(256)
void gemm_bf16_lds(const __bf16* __restrict__ A,
                   const __bf16* __restrict__ W,
                   const float* __restrict__ bias,
                   TC* __restrict__ C,
                   float out_scale) {
  __shared__ alignas(16) __bf16 As[64][64];
  __shared__ alignas(16) __bf16 Ws[64][64];

  const int t = threadIdx.x;
  const int lane = t & 63;
  const int w = t >> 6;
  const int wr = w >> 1;
  const int wc = w & 1;
  const int col = lane & 15;
  const int quad = lane >> 4;
  const int m_blk = blockIdx.y * 64;
  const int n_blk = blockIdx.x * 64;

  const int srow = t >> 3;
  const int scol = (t & 7) * 8;

  f32x4 acc[2][2] = {};

  for (int k0 = 0; k0 < DMODEL; k0 += BK) {
    __syncthreads();
    #pragma unroll
    for (int p = 0; p < 2; ++p)
      load_lds_16B(A + (size_t)(m_blk + p * 32 + srow) * DMODEL + k0 + scol,
                   &As[p * 32 + srow][scol]);
    #pragma unroll
    for (int p = 0; p < 2; ++p)
      load_lds_16B(W + (size_t)(n_blk + p * 32 + srow) * DMODEL + k0 + scol,
                   &Ws[p * 32 + srow][scol]);
    __syncthreads();

    #pragma unroll
    for (int kh = 0; kh < BK; kh += 32) {
      bf16x8 af[2], bfr[2];
      #pragma unroll
      for (int at = 0; at < 2; ++at)
        af[at] = *(const bf16x8*)&As[wr * 32 + at * 16 + col][kh + quad * 8];
      #pragma unroll
      for (int bt = 0; bt < 2; ++bt)
        bfr[bt] = *(const bf16x8*)&Ws[wc * 32 + bt * 16 + col][kh + quad * 8];
      #pragma unroll
      for (int at = 0; at < 2; ++at)
        #pragma unroll
        for (int bt = 0; bt < 2; ++bt)
          acc[at][bt] = __builtin_amdgcn_mfma_f32_16x16x32_bf16(
              af[at], bfr[bt], acc[at][bt], 0, 0, 0);
    }
  }

  #pragma unroll
  for (int at = 0; at < 2; ++at) {
    #pragma unroll
    for (int bt = 0; bt < 2; ++bt) {
      const int n = n_blk + wc * 32 + bt * 16 + col;
      const float b = bias[n];
      #pragma unroll
      for (int i = 0; i < 4; ++i) {
        const int m = m_blk + wr * 32 + at * 16 + quad * 4 + i;
        const float v = (acc[at][bt][i] + b) * out_scale;
        if constexpr (TRANS_C) store_c(&C[(size_t)n * SEQ + m], v);
        else                   store_c(&C[(size_t)m * DMODEL + n], v);
      }
    }
  }
}

// ---------------------------------------------------------------------------
// FALLBACK GEMM — identical to R10..R14 (only used if ws_size < 40 MB).
// ---------------------------------------------------------------------------
constexpr int LDK = 72;

template <typename TA, typename TC, bool TRANS_C>
__global__ __launch_bounds__(256)
void gemm_tiled(const TA* __restrict__ A,
                const float* __restrict__ W,
                const float* __restrict__ bias,
                TC* __restrict__ C,
                float out_scale) {
  __shared__ alignas(16) __bf16 As[128][LDK];
  __shared__ alignas(16) __bf16 Ws[64][LDK];

  const int t = threadIdx.x;
  const int lane = t & 63;
  const int w = t >> 6;
  const int wr = w >> 1;
  const int wc = w & 1;
  const int col = lane & 15;
  const int quad = lane >> 4;
  const int m_blk = blockIdx.y * 128;
  const int n_blk = blockIdx.x * 64;

  f32x4 acc[4][2] = {};

  for (int k0 = 0; k0 < DMODEL; k0 += BK) {
    __syncthreads();
    if constexpr (std::is_same<TA, float>::value) {
      #pragma unroll
      for (int p = 0; p < 8; ++p) {
        const int r = p * 16 + (t >> 4);
        const int c = (t & 15) * 4;
        const float4 v =
            *(const float4*)(A + (size_t)(m_blk + r) * DMODEL + k0 + c);
        bf16x4 b = {(__bf16)v.x, (__bf16)v.y, (__bf16)v.z, (__bf16)v.w};
        *(bf16x4*)&As[r][c] = b;
      }
    } else {
      #pragma unroll
      for (int p = 0; p < 4; ++p) {
        const int r = p * 32 + (t >> 3);
        const int c = (t & 7) * 8;
        *(bf16x8*)&As[r][c] =
            *(const bf16x8*)((const __bf16*)A + (size_t)(m_blk + r) * DMODEL + k0 + c);
      }
    }
    #pragma unroll
    for (int p = 0; p < 4; ++p) {
      const int r = p * 16 + (t >> 4);
      const int c = (t & 15) * 4;
      const float4 v =
          *(const float4*)(W + (size_t)(n_blk + r) * DMODEL + k0 + c);
      bf16x4 b = {(__bf16)v.x, (__bf16)v.y, (__bf16)v.z, (__bf16)v.w};
      *(bf16x4*)&Ws[r][c] = b;
    }
    __syncthreads();

    #pragma unroll
    for (int kh = 0; kh < BK; kh += 32) {
      bf16x8 af[4], bfr[2];
      #pragma unroll
      for (int at = 0; at < 4; ++at)
        af[at] = *(const bf16x8*)&As[wr * 64 + at * 16 + col][kh + quad * 8];
      #pragma unroll
      for (int bt = 0; bt < 2; ++bt)
        bfr[bt] = *(const bf16x8*)&Ws[wc * 32 + bt * 16 + col][kh + quad * 8];
      #pragma unroll
      for (int at = 0; at < 4; ++at)
        #pragma unroll
        for (int bt = 0; bt < 2; ++bt)
          acc[at][bt] = __builtin_amdgcn_mfma_f32_16x16x32_bf16(
              af[at], bfr[bt], acc[at][bt], 0, 0, 0);
    }
  }

  #pragma unroll
  for (int at = 0; at < 4; ++at) {
    #pragma unroll
    for (int bt = 0; bt < 2; ++bt) {
      const int n = n_blk + wc * 32 + bt * 16 + col;
      const float b = bias[n];
      #pragma unroll
      for (int i = 0; i < 4; ++i) {
        const int m = m_blk + wr * 64 + at * 16 + quad * 4 + i;
        const float v = (acc[at][bt][i] + b) * out_scale;
        if constexpr (TRANS_C) store_c(&C[(size_t)n * SEQ + m], v);
        else                   store_c(&C[(size_t)m * DMODEL + n], v);
      }
    }
  }
}

// ---------------------------------------------------------------------------
// MFMA flash attention, SPLIT-K over keys — BYTE-IDENTICAL to R14 (113 us).
// ---------------------------------------------------------------------------
constexpr int LDP = 72;
constexpr float SHIFT = 8.0f;

__global__ __launch_bounds__(256)
void flash_attn_split(const __hip_bfloat16* __restrict__ Q,
                      const __hip_bfloat16* __restrict__ K,
                      const __hip_bfloat16* __restrict__ Vt,
                      __hip_bfloat16* __restrict__ Opart,
                      float* __restrict__ lsum_g) {
  __shared__ alignas(16) __hip_bfloat16 kt[64][LDP];
  __shared__ alignas(16) __hip_bfloat16 vtt[DKH][LDP];
  __shared__ alignas(16) __hip_bfloat16 plT[4][32][LDP];

  const int t = threadIdx.x;
  const int lane = t & 63;
  const int w = t >> 6;
  const int h = blockIdx.y;
  const int q0 = blockIdx.x * 128;
  const int z = blockIdx.z;
  const int col = lane & 15;
  const int quad = lane >> 4;

  bf16x8 qf[2][2];
  #pragma unroll
  for (int rg = 0; rg < 2; ++rg) {
    const __hip_bfloat16* qptr =
        Q + (size_t)(q0 + w * 32 + rg * 16 + col) * DMODEL + h * DKH + quad * 8;
    qf[rg][0] = *(const bf16x8*)qptr;
    qf[rg][1] = *(const bf16x8*)(qptr + 32);
  }

  f32x4 acc_o[2][4] = {};
  float lsumq[2] = {0.f, 0.f};

  const int sr = t >> 2;
  const int sc = (t & 3) * 16;

  const int kbeg = z * (SEQ / 2);
  const int kend = kbeg + SEQ / 2;

  for (int k0 = kbeg; k0 < kend; k0 += 64) {
    __syncthreads();
    const __hip_bfloat16* kg = K + (size_t)(k0 + sr) * DMODEL + h * DKH + sc;
    *(bf16x8*)&kt[sr][sc]     = *(const bf16x8*)kg;
    *(bf16x8*)&kt[sr][sc + 8] = *(const bf16x8*)(kg + 8);
    const __hip_bfloat16* vg = Vt + (size_t)(h * DKH + sr) * SEQ + k0 + sc;
    *(bf16x8*)&vtt[sr][sc]     = *(const bf16x8*)vg;
    *(bf16x8*)&vtt[sr][sc + 8] = *(const bf16x8*)(vg + 8);
    __syncthreads();

    #pragma unroll
    for (int jt = 0; jt < 4; ++jt) {
      const bf16x8 kf0 = *(const bf16x8*)&kt[jt * 16 + col][quad * 8];
      const bf16x8 kf1 = *(const bf16x8*)&kt[jt * 16 + col][quad * 8 + 32];
      #pragma unroll
      for (int rg = 0; rg < 2; ++rg) {
        f32x4 zz = {0.f, 0.f, 0.f, 0.f};
        zz = __builtin_amdgcn_mfma_f32_16x16x32_bf16(kf0, qf[rg][0], zz, 0, 0, 0);
        zz = __builtin_amdgcn_mfma_f32_16x16x32_bf16(kf1, qf[rg][1], zz, 0, 0, 0);
        bf16x4 pk;
        #pragma unroll
        for (int r = 0; r < 4; ++r) {
          const float p = __expf(zz[r] - SHIFT);
          lsumq[rg] += p;
          pk[r] = (__bf16)p;
        }
        *(bf16x4*)&plT[w][rg * 16 + col][jt * 16 + quad * 4] = pk;
      }
    }

    bf16x8 pa[2][2];
    #pragma unroll
    for (int rg = 0; rg < 2; ++rg) {
      pa[rg][0] = *(const bf16x8*)&plT[w][rg * 16 + col][quad * 8];
      pa[rg][1] = *(const bf16x8*)&plT[w][rg * 16 + col][quad * 8 + 32];
    }
    #pragma unroll
    for (int jt = 0; jt < 4; ++jt) {
      const bf16x8 vb0 = *(const bf16x8*)&vtt[jt * 16 + col][quad * 8];
      const bf16x8 vb1 = *(const bf16x8*)&vtt[jt * 16 + col][quad * 8 + 32];
      #pragma unroll
      for (int rg = 0; rg < 2; ++rg) {
        acc_o[rg][jt] = __builtin_amdgcn_mfma_f32_16x16x32_bf16(
            pa[rg][0], vb0, acc_o[rg][jt], 0, 0, 0);
        acc_o[rg][jt] = __builtin_amdgcn_mfma_f32_16x16x32_bf16(
            pa[rg][1], vb1, acc_o[rg][jt], 0, 0, 0);
      }
    }
  }

  #pragma unroll
  for (int rg = 0; rg < 2; ++rg) {
    lsumq[rg] += __shfl_xor(lsumq[rg], 16);
    lsumq[rg] += __shfl_xor(lsumq[rg], 32);
  }
  if (lane < 16) {
    #pragma unroll
    for (int rg = 0; rg < 2; ++rg)
      lsum_g[((size_t)z * NH + h) * SEQ + q0 + w * 32 + rg * 16 + lane] = lsumq[rg];
  }

  __hip_bfloat16* O = Opart + (size_t)z * SEQ * DMODEL;
  #pragma unroll
  for (int rg = 0; rg < 2; ++rg) {
    #pragma unroll
    for (int jt = 0; jt < 4; ++jt) {
      #pragma unroll
      for (int r = 0; r < 4; ++r) {
        const int qr = q0 + w * 32 + rg * 16 + quad * 4 + r;
        const int c = h * DKH + jt * 16 + col;
        O[(size_t)qr * DMODEL + c] = __float2bfloat16(acc_o[rg][jt][r]);
      }
    }
  }
}

// Combine: Ao = (O0 + O1) / (l0 + l1) — identical to R14.
__global__ __launch_bounds__(256)
void attn_combine(const __hip_bfloat16* __restrict__ Op,
                  const float* __restrict__ ls,
                  __hip_bfloat16* __restrict__ Ao) {
  const size_t i = ((size_t)blockIdx.x * 256 + threadIdx.x) * 8;
  const int qrow = (int)(i >> 10);
  const int h = (int)((i & 1023) >> 6);
  const float inv = 1.f / (ls[(size_t)h * SEQ + qrow] +
                           ls[(size_t)(NH + h) * SEQ + qrow]);
  const bf16x8 a = *(const bf16x8*)(Op + i);
  const bf16x8 b = *(const bf16x8*)(Op + (size_t)SEQ * DMODEL + i);
  bf16x8 r;
  #pragma unroll
  for (int j = 0; j < 8; ++j)
    r[j] = (__bf16)(((float)a[j] + (float)b[j]) * inv);
  *(bf16x8*)(Ao + i) = r;
}

// ---------------------------------------------------------------------------
// FALLBACK flash (R12 mono) — used only if ws_size < 40 MB.
// ---------------------------------------------------------------------------
__global__ __launch_bounds__(256)
void flash_attn_mono(const __hip_bfloat16* __restrict__ Q,
                     const __hip_bfloat16* __restrict__ K,
                     const __hip_bfloat16* __restrict__ Vt,
                     __hip_bfloat16* __restrict__ O) {
  __shared__ alignas(16) __hip_bfloat16 kt[64][LDP];
  __shared__ alignas(16) __hip_bfloat16 vtt[DKH][LDP];
  __shared__ alignas(16) __hip_bfloat16 plT[4][32][LDP];

  const int t = threadIdx.x;
  const int lane = t & 63;
  const int w = t >> 6;
  const int h = blockIdx.y;
  const int q0 = blockIdx.x * 128;
  const int col = lane & 15;
  const int quad = lane >> 4;

  bf16x8 qf[2][2];
  #pragma unroll
  for (int rg = 0; rg < 2; ++rg) {
    const __hip_bfloat16* qptr =
        Q + (size_t)(q0 + w * 32 + rg * 16 + col) * DMODEL + h * DKH + quad * 8;
    qf[rg][0] = *(const bf16x8*)qptr;
    qf[rg][1] = *(const bf16x8*)(qptr + 32);
  }

  f32x4 acc_o[2][4] = {};
  float lsumq[2] = {0.f, 0.f};
  const int sr = t >> 2;
  const int sc = (t & 3) * 16;

  for (int k0 = 0; k0 < SEQ; k0 += 64) {
    __syncthreads();
    const __hip_bfloat16* kg = K + (size_t)(k0 + sr) * DMODEL + h * DKH + sc;
    *(bf16x8*)&kt[sr][sc]     = *(const bf16x8*)kg;
    *(bf16x8*)&kt[sr][sc + 8] = *(const bf16x8*)(kg + 8);
    const __hip_bfloat16* vg = Vt + (size_t)(h * DKH + sr) * SEQ + k0 + sc;
    *(bf16x8*)&vtt[sr][sc]     = *(const bf16x8*)vg;
    *(bf16x8*)&vtt[sr][sc + 8] = *(const bf16x8*)(vg + 8);
    __syncthreads();

    #pragma unroll
    for (int jt = 0; jt < 4; ++jt) {
      const bf16x8 kf0 = *(const bf16x8*)&kt[jt * 16 + col][quad * 8];
      const bf16x8 kf1 = *(const bf16x8*)&kt[jt * 16 + col][quad * 8 + 32];
      #pragma unroll
      for (int rg = 0; rg < 2; ++rg) {
        f32x4 zz = {0.f, 0.f, 0.f, 0.f};
        zz = __builtin_amdgcn_mfma_f32_16x16x32_bf16(kf0, qf[rg][0], zz, 0, 0, 0);
        zz = __builtin_amdgcn_mfma_f32_16x16x32_bf16(kf1, qf[rg][1], zz, 0, 0, 0);
        bf16x4 pk;
        #pragma unroll
        for (int r = 0; r < 4; ++r) {
          const float p = __expf(zz[r] - SHIFT);
          lsumq[rg] += p;
          pk[r] = (__bf16)p;
        }
        *(bf16x4*)&plT[w][rg * 16 + col][jt * 16 + quad * 4] = pk;
      }
    }

    bf16x8 pa[2][2];
    #pragma unroll
    for (int rg = 0; rg < 2; ++rg) {
      pa[rg][0] = *(const bf16x8*)&plT[w][rg * 16 + col][quad * 8];
      pa[rg][1] = *(const bf16x8*)&plT[w][rg * 16 + col][quad * 8 + 32];
    }
    #pragma unroll
    for (int jt = 0; jt < 4; ++jt) {
      const bf16x8 vb0 = *(const bf16x8*)&vtt[jt * 16 + col][quad * 8];
      const bf16x8 vb1 = *(const bf16x8*)&vtt[jt * 16 + col][quad * 8 + 32];
      #pragma unroll
      for (int rg = 0; rg < 2; ++rg) {
        acc_o[rg][jt] = __builtin_amdgcn_mfma_f32_16x16x32_bf16(
            pa[rg][0], vb0, acc_o[rg][jt], 0, 0, 0);
        acc_o[rg][jt] = __builtin_amdgcn_mfma_f32_16x16x32_bf16(
            pa[rg][1], vb1, acc_o[rg][jt], 0, 0, 0);
      }
    }
  }

  #pragma unroll
  for (int rg = 0; rg < 2; ++rg) {
    lsumq[rg] += __shfl_xor(lsumq[rg], 16);
    lsumq[rg] += __shfl_xor(lsumq[rg], 32);
  }
  float invr[2][4];
  #pragma unroll
  for (int rg = 0; rg < 2; ++rg)
    #pragma unroll
    for (int r = 0; r < 4; ++r)
      invr[rg][r] = 1.f / __shfl(lsumq[rg], quad * 4 + r);

  #pragma unroll
  for (int rg = 0; rg < 2; ++rg) {
    #pragma unroll
    for (int jt = 0; jt < 4; ++jt) {
      #pragma unroll
      for (int r = 0; r < 4; ++r) {
        const int qr = q0 + w * 32 + rg * 16 + quad * 4 + r;
        const int c = h * DKH + jt * 16 + col;
        O[(size_t)qr * DMODEL + c] = __float2bfloat16(acc_o[rg][jt][r] * invr[rg][r]);
      }
    }
  }
}

// ---------------------------------------------------------------------------
// Interface (R7-proven): inputs fp32 dict-order, output fp32.
// FAST path (ws_size >= 40 MB), R15 plan (6 dispatches):
//   d_out: Qp [0,8M) | Xq [8,16M)
//   ws: Kp[0,8) Vt[8,16) | Xk[16,24)->Opart0->Ao | Xv[24,32)->Opart1 |
//       Wqb[32,34)->lsum | Wkb[34,36) Wvb[36,38) Wob[38,40)
//   final GEMM writes d_out fp32 directly.
// ---------------------------------------------------------------------------
extern "C" void kernel_launch(void* const* d_in, const int* in_sizes, int n_in,
                              void* d_out, int out_size, void* d_ws, size_t ws_size,
                              hipStream_t stream) {
  const float* query = (const float*)d_in[0];
  const float* key   = (const float*)d_in[1];
  const float* value = (const float*)d_in[2];
  const float* W_q   = (const float*)d_in[3];
  const float* b_q   = (const float*)d_in[4];
  const float* W_k   = (const float*)d_in[5];
  const float* b_k   = (const float*)d_in[6];
  const float* W_v   = (const float*)d_in[7];
  const float* b_v   = (const float*)d_in[8];
  const float* W_o   = (const float*)d_in[9];
  const float* b_o   = (const float*)d_in[10];

  float* out = (float*)d_out;
  const size_t mat = (size_t)SEQ * DMODEL;
  const size_t MB = 1024 * 1024;

  char* ws = (char*)d_ws;
  __hip_bfloat16* Qp = (__hip_bfloat16*)d_out;
  __hip_bfloat16* Kp = (__hip_bfloat16*)ws;
  __hip_bfloat16* Vt = Kp + mat;

  dim3 gblock(256);

  if (ws_size >= 40 * MB) {
    __bf16* Xq  = (__bf16*)((char*)d_out + 8 * MB);
    __bf16* Xk  = (__bf16*)(ws + 16 * MB);
    __bf16* Xv  = (__bf16*)(ws + 24 * MB);
    __bf16* Wqb = (__bf16*)(ws + 32 * MB);
    __bf16* Wkb = (__bf16*)(ws + 34 * MB);
    __bf16* Wvb = (__bf16*)(ws + 36 * MB);
    __bf16* Wob = (__bf16*)(ws + 38 * MB);
    __hip_bfloat16* Opart = (__hip_bfloat16*)(ws + 16 * MB);  // 2 x 8 MB
    float* lsum = (float*)(ws + 32 * MB);                     // 512 KB
    __hip_bfloat16* Ao = (__hip_bfloat16*)(ws + 16 * MB);     // combine in place

    hipLaunchKernelGGL(cvt_all, dim3(8192), gblock, 0, stream,
                       query, key, value, W_q, W_k, W_v, W_o,
                       Xq, Xk, Xv, Wqb, Wkb, Wvb, Wob);

    dim3 pgrid(DMODEL / 64, SEQ / 64, 3);  // (16, 64, 3) = 3072 blocks
    hipLaunchKernelGGL(gemm3_proj, pgrid, gblock, 0, stream,
                       Xq, Xk, Xv, Wqb, Wkb, Wvb, b_q, b_k, b_v, Qp, Kp, Vt);

    dim3 agrid(SEQ / 128, NH, 2);  // (32, 16, 2) = 1024 blocks
    hipLaunchKernelGGL(flash_attn_split, agrid, gblock, 0, stream,
                       Qp, Kp, Vt, Opart, lsum);
    hipLaunchKernelGGL(attn_combine, dim3(2048), gblock, 0, stream,
                       Opart, lsum, Ao);

    dim3 ggrid(DMODEL / 64, SEQ / 64);  // (16, 64) = 1024 blocks
    hipLaunchKernelGGL((gemm_bf16_lds<float, false>), ggrid, gblock, 0, stream,
                       (const __bf16*)Ao, Wob, b_o, out, 1.0f);
  } else {
    // fallback: R10-proven plan (16 MB ws)
    __hip_bfloat16* Ao = Qp + mat;
    float* Cw = (float*)d_ws;
    dim3 fgrid(DMODEL / 64, SEQ / 128);
    hipLaunchKernelGGL((gemm_tiled<float, __hip_bfloat16, false>), fgrid, gblock,
                       0, stream, query, W_q, b_q, Qp, SCALE);
    hipLaunchKernelGGL((gemm_tiled<float, __hip_bfloat16, false>), fgrid, gblock,
                       0, stream, key, W_k, b_k, Kp, 1.0f);
    hipLaunchKernelGGL((gemm_tiled<float, __hip_bfloat16, true>), fgrid, gblock,
                       0, stream, value, W_v, b_v, Vt, 1.0f);
    dim3 agrid(SEQ / 128, NH);
    hipLaunchKernelGGL(flash_attn_mono, agrid, gblock, 0, stream, Qp, Kp, Vt, Ao);
    hipLaunchKernelGGL((gemm_tiled<__hip_bfloat16, float, false>), fgrid, gblock,
                       0, stream, Ao, W_o, b_o, Cw, 1.0f);
    hipMemcpyAsync(out, Cw, mat * sizeof(float), hipMemcpyDeviceToDevice, stream);
  }
}